// Round 5
// baseline (99.973 us; speedup 1.0000x reference)
//
#include <hip/hip_runtime.h>
#include <hip/hip_cooperative_groups.h>

namespace cg = cooperative_groups;

#define TILE 256   // square tile side; block = 256 threads, j per-lane

__global__ __launch_bounds__(256) void cindex_fused_kernel(
    const float* __restrict__ risk,
    const float* __restrict__ tim,
    const int*   __restrict__ evt,
    unsigned int* __restrict__ part,   // SoA: [0,nblk)=conc, [nblk,2n)=tie, [2n,3n)=comp
    float* __restrict__ out,
    int n, int nblk)
{
    const int t = blockIdx.x;
    // Decode lower-triangle pair (p >= q): p*(p+1)/2 <= t < (p+1)*(p+2)/2
    int p = (int)((sqrtf(8.0f * (float)t + 1.0f) - 1.0f) * 0.5f);
    while ((p + 1) * (p + 2) / 2 <= t) ++p;
    while (p * (p + 1) / 2 > t) --p;
    const int q = t - p * (p + 1) / 2;

    const int i0 = q * TILE;          // i-tile (smaller index)
    const int j0 = p * TILE;          // j-tile (larger index)
    const bool diag = (p == q);

    __shared__ float s_t[TILE];
    __shared__ float s_r[TILE];
    __shared__ unsigned int s_mask[4][2];
    __shared__ unsigned int s_part[4][3];

    const int tid = threadIdx.x;

    // Stage the i-tile; build one 64-bit event mask per wave.
    {
        int i = i0 + tid;
        bool inb = (i < n);
        s_t[tid] = inb ? tim[i]  : 0.0f;
        s_r[tid] = inb ? risk[i] : 0.0f;
        unsigned long long m = __ballot(inb && (evt[i] == 1));
        if ((tid & 63) == 0) {
            s_mask[tid >> 6][0] = (unsigned int)m;
            s_mask[tid >> 6][1] = (unsigned int)(m >> 32);
        }
    }
    __syncthreads();

    // Per-lane j data, register-resident for the whole block.
    const int j  = j0 + tid;
    const bool jv = (j < n);
    const float tj = jv ? tim[j]  : 0.0f;
    const float rj = jv ? risk[j] : 0.0f;
    const int  ejv = jv ? evt[j]  : -1;
    const bool ej1 = (ejv == 1);
    const bool ej0 = (ejv == 0);

    unsigned int nComp = 0, nConc = 0, nTie = 0;

    #pragma unroll
    for (int s = 0; s < 4; ++s) {
        // Broadcast this sub-tile's event mask into SGPRs (scalar loop control).
        unsigned int lo = __builtin_amdgcn_readfirstlane((int)s_mask[s][0]);
        unsigned int hi = __builtin_amdgcn_readfirstlane((int)s_mask[s][1]);
        unsigned long long em = (((unsigned long long)hi) << 32) | (unsigned long long)lo;
        const int ibase = s * 64;

        if (!diag) {
            // Off-diagonal: every staged i < every j (j0 >= i0+TILE).
            while (em) {
                int ii = __builtin_ctzll(em); em &= (em - 1);
                float ti = s_t[ibase + ii];
                float ri = s_r[ibase + ii];
                bool lt  = ti < tj;
                bool gt  = ti > tj;
                bool rgt = ri > rj;
                bool rlt = ri < rj;
                bool req = ri == rj;
                bool comp = ej1 | (ej0 & lt);
                bool conc = (ej1 & ((lt & rgt) | (gt & rlt))) | (ej0 & lt & rgt);
                nComp += (unsigned int)comp;
                nConc += (unsigned int)conc;
                nTie  += (unsigned int)(comp & req);
            }
        } else {
            // Diagonal tile: j0 == i0, enforce j > i  <=>  tid > ibase+ii.
            while (em) {
                int ii = __builtin_ctzll(em); em &= (em - 1);
                float ti = s_t[ibase + ii];
                float ri = s_r[ibase + ii];
                bool ok  = tid > (ibase + ii);
                bool lt  = ti < tj;
                bool gt  = ti > tj;
                bool rgt = ri > rj;
                bool rlt = ri < rj;
                bool req = ri == rj;
                bool comp = (ej1 | (ej0 & lt)) & ok;
                bool conc = ((ej1 & ((lt & rgt) | (gt & rlt))) | (ej0 & lt & rgt)) & ok;
                nComp += (unsigned int)comp;
                nConc += (unsigned int)conc;
                nTie  += (unsigned int)(comp & req);
            }
        }
    }

    // Wave-level shuffle reduction (64 lanes).
    for (int off = 32; off > 0; off >>= 1) {
        nComp += __shfl_down(nComp, off, 64);
        nConc += __shfl_down(nConc, off, 64);
        nTie  += __shfl_down(nTie,  off, 64);
    }
    const int wid  = tid >> 6;
    const int lane = tid & 63;
    if (lane == 0) {
        s_part[wid][0] = nConc;
        s_part[wid][1] = nTie;
        s_part[wid][2] = nComp;
    }
    __syncthreads();
    if (tid == 0) {
        unsigned int c0 = 0, c1 = 0, c2 = 0;
        #pragma unroll
        for (int w = 0; w < 4; ++w) {
            c0 += s_part[w][0];
            c1 += s_part[w][1];
            c2 += s_part[w][2];
        }
        part[t] = c0;                // conc
        part[nblk + t] = c1;         // tie
        part[2 * nblk + t] = c2;     // comp
    }

    // Make partials visible device-wide (cross-XCD), then grid-sync.
    __threadfence();
    cg::this_grid().sync();

    // Block 0 finalizes.
    if (blockIdx.x == 0) {
        unsigned int c0 = 0, c1 = 0, c2 = 0;
        for (int i = tid; i < nblk; i += 256) {
            c0 += part[i];
            c1 += part[nblk + i];
            c2 += part[2 * nblk + i];
        }
        for (int off = 32; off > 0; off >>= 1) {
            c0 += __shfl_down(c0, off, 64);
            c1 += __shfl_down(c1, off, 64);
            c2 += __shfl_down(c2, off, 64);
        }
        if (lane == 0) {
            s_part[wid][0] = c0;
            s_part[wid][1] = c1;
            s_part[wid][2] = c2;
        }
        __syncthreads();
        if (tid == 0) {
            unsigned int t0 = 0, t1 = 0, t2 = 0;
            #pragma unroll
            for (int w = 0; w < 4; ++w) {
                t0 += s_part[w][0];
                t1 += s_part[w][1];
                t2 += s_part[w][2];
            }
            double conc = (double)t0;
            double tie  = (double)t1;
            double comp = (double)t2;
            float c;
            if (comp > 0.0) {
                c = (float)((conc + 0.5 * tie) / comp);
            } else {
                c = 0.5f;
            }
            out[0] = 1.0f - c;
        }
    }
}

extern "C" void kernel_launch(void* const* d_in, const int* in_sizes, int n_in,
                              void* d_out, int out_size, void* d_ws, size_t ws_size,
                              hipStream_t stream)
{
    const float* risk = (const float*)d_in[0];   // (B,1) f32, flat B
    const float* tim  = (const float*)d_in[1];   // (B,)  f32
    const int*   evt  = (const int*)d_in[2];     // (B,)  i32
    float* out = (float*)d_out;
    unsigned int* part = (unsigned int*)d_ws;

    int n = in_sizes[1];
    int nt = (n + TILE - 1) / TILE;        // tile rows (32 for n=8192)
    int nblk = nt * (nt + 1) / 2;          // triangular tile count (528)

    void* args[] = { (void*)&risk, (void*)&tim, (void*)&evt,
                     (void*)&part, (void*)&out, (void*)&n, (void*)&nblk };
    hipLaunchCooperativeKernel((const void*)cindex_fused_kernel,
                               dim3(nblk), dim3(256), args, 0, stream);
}

// Round 6
// 20.795 us; speedup vs baseline: 4.8076x; 4.8076x over previous
//
#include <hip/hip_runtime.h>

#define TILE 256   // square tile side; block = 256 threads, j per-lane

__global__ __launch_bounds__(256) void cindex_pairs_kernel(
    const float* __restrict__ risk,
    const float* __restrict__ tim,
    const int*   __restrict__ evt,
    unsigned int* __restrict__ part,   // SoA: [0,nblk)=conc, [nblk,2n)=tie, [2n,3n)=comp
    int n, int nblk)
{
    const int t = blockIdx.x;
    // Decode lower-triangle pair (p >= q): p*(p+1)/2 <= t < (p+1)*(p+2)/2
    int p = (int)((sqrtf(8.0f * (float)t + 1.0f) - 1.0f) * 0.5f);
    while ((p + 1) * (p + 2) / 2 <= t) ++p;
    while (p * (p + 1) / 2 > t) --p;
    const int q = t - p * (p + 1) / 2;

    const int i0 = q * TILE;          // i-tile (smaller index)
    const int j0 = p * TILE;          // j-tile (larger index)
    const bool diag = (p == q);

    __shared__ float2 s_pack[TILE];        // compacted (t_i, r_i) of event-i's
    __shared__ int    s_idx[TILE];         // compacted tid of event-i's (diag check)
    __shared__ unsigned int s_cnt[4];      // per-wave event counts
    __shared__ unsigned int s_part[4][3];

    const int tid  = threadIdx.x;
    const int wid  = tid >> 6;
    const int lane = tid & 63;

    // ---- Stage: compact event-i's into a dense LDS array ----
    {
        int i = i0 + tid;
        bool inb = (i < n);
        float tv = inb ? tim[i]  : 0.0f;
        float rv = inb ? risk[i] : 0.0f;
        bool ev = inb && (evt[i] == 1);
        unsigned long long m = __ballot(ev);
        if (lane == 0) s_cnt[wid] = (unsigned int)__popcll(m);
        __syncthreads();
        int base = 0;
        #pragma unroll
        for (int w = 0; w < 4; ++w) base += (w < wid) ? (int)s_cnt[w] : 0;
        int pos = base + (int)__popcll(m & ((1ull << lane) - 1ull));
        if (ev) { s_pack[pos] = make_float2(tv, rv); s_idx[pos] = tid; }
    }
    __syncthreads();

    int cnt = (int)(s_cnt[0] + s_cnt[1] + s_cnt[2] + s_cnt[3]);
    cnt = __builtin_amdgcn_readfirstlane(cnt);   // scalar loop bound

    // ---- Per-lane j data, register-resident ----
    const int j  = j0 + tid;
    const bool jv = (j < n);
    const float tj = jv ? tim[j]  : 0.0f;
    const float rj = jv ? risk[j] : 0.0f;
    const int  ejv = jv ? evt[j]  : -1;
    const bool ej1 = (ejv == 1);
    const bool ej0 = (ejv == 0);

    unsigned int nComp = 0, nConc = 0, nTie = 0;

    if (!diag) {
        // Off-diagonal: every staged i < every j (j0 >= i0+TILE).
        #pragma unroll 4
        for (int k = 0; k < cnt; ++k) {
            float2 tr = s_pack[k];          // broadcast ds_read_b64
            float ti = tr.x, ri = tr.y;
            bool lt  = ti < tj;
            bool gt  = ti > tj;
            bool rgt = ri > rj;
            bool rlt = ri < rj;
            bool req = ri == rj;
            bool comp = ej1 | (ej0 & lt);
            bool conc = (ej1 & ((lt & rgt) | (gt & rlt))) | (ej0 & lt & rgt);
            nComp += (unsigned int)comp;
            nConc += (unsigned int)conc;
            nTie  += (unsigned int)(comp & req);
        }
    } else {
        // Diagonal tile: j0 == i0, enforce j > i  <=>  tid > staged tid.
        #pragma unroll 4
        for (int k = 0; k < cnt; ++k) {
            float2 tr = s_pack[k];
            int   ii  = s_idx[k];
            float ti = tr.x, ri = tr.y;
            bool ok  = tid > ii;
            bool lt  = ti < tj;
            bool gt  = ti > tj;
            bool rgt = ri > rj;
            bool rlt = ri < rj;
            bool req = ri == rj;
            bool comp = (ej1 | (ej0 & lt)) & ok;
            bool conc = ((ej1 & ((lt & rgt) | (gt & rlt))) | (ej0 & lt & rgt)) & ok;
            nComp += (unsigned int)comp;
            nConc += (unsigned int)conc;
            nTie  += (unsigned int)(comp & req);
        }
    }

    // ---- Wave-level shuffle reduction (64 lanes) ----
    for (int off = 32; off > 0; off >>= 1) {
        nComp += __shfl_down(nComp, off, 64);
        nConc += __shfl_down(nConc, off, 64);
        nTie  += __shfl_down(nTie,  off, 64);
    }
    if (lane == 0) {
        s_part[wid][0] = nConc;
        s_part[wid][1] = nTie;
        s_part[wid][2] = nComp;
    }
    __syncthreads();
    if (tid == 0) {
        unsigned int c0 = 0, c1 = 0, c2 = 0;
        #pragma unroll
        for (int w = 0; w < 4; ++w) {
            c0 += s_part[w][0];
            c1 += s_part[w][1];
            c2 += s_part[w][2];
        }
        part[t] = c0;                // conc
        part[nblk + t] = c1;         // tie
        part[2 * nblk + t] = c2;     // comp
    }
}

__global__ __launch_bounds__(256) void cindex_reduce_kernel(
    const unsigned int* __restrict__ part,
    float* __restrict__ out, int nblk)
{
    const int tid = threadIdx.x;
    unsigned int c0 = 0, c1 = 0, c2 = 0;
    for (int i = tid; i < nblk; i += 256) {
        c0 += part[i];
        c1 += part[nblk + i];
        c2 += part[2 * nblk + i];
    }
    for (int off = 32; off > 0; off >>= 1) {
        c0 += __shfl_down(c0, off, 64);
        c1 += __shfl_down(c1, off, 64);
        c2 += __shfl_down(c2, off, 64);
    }
    __shared__ unsigned int s_part[4][3];
    const int wid  = tid >> 6;
    const int lane = tid & 63;
    if (lane == 0) {
        s_part[wid][0] = c0;
        s_part[wid][1] = c1;
        s_part[wid][2] = c2;
    }
    __syncthreads();
    if (tid == 0) {
        unsigned int t0 = 0, t1 = 0, t2 = 0;
        #pragma unroll
        for (int w = 0; w < 4; ++w) {
            t0 += s_part[w][0];
            t1 += s_part[w][1];
            t2 += s_part[w][2];
        }
        double conc = (double)t0;
        double tie  = (double)t1;
        double comp = (double)t2;
        float c;
        if (comp > 0.0) {
            c = (float)((conc + 0.5 * tie) / comp);
        } else {
            c = 0.5f;
        }
        out[0] = 1.0f - c;
    }
}

extern "C" void kernel_launch(void* const* d_in, const int* in_sizes, int n_in,
                              void* d_out, int out_size, void* d_ws, size_t ws_size,
                              hipStream_t stream)
{
    const float* risk = (const float*)d_in[0];   // (B,1) f32, flat B
    const float* tim  = (const float*)d_in[1];   // (B,)  f32
    const int*   evt  = (const int*)d_in[2];     // (B,)  i32
    float* out = (float*)d_out;
    unsigned int* part = (unsigned int*)d_ws;

    const int n = in_sizes[1];
    const int nt = (n + TILE - 1) / TILE;        // tile rows (32 for n=8192)
    const int nblk = nt * (nt + 1) / 2;          // triangular tile count (528)

    cindex_pairs_kernel<<<dim3(nblk), 256, 0, stream>>>(risk, tim, evt, part, n, nblk);
    cindex_reduce_kernel<<<1, 256, 0, stream>>>(part, out, nblk);
}